// Round 2
// 218.498 us; speedup vs baseline: 1.1319x; 1.1319x over previous
//
#include <hip/hip_runtime.h>
#include <math.h>

#define D 256
#define NX 16
#define L 2048
#define NBATCH 8
#define NTOK (NBATCH * L)
#define CL 32
#define NCH (L / CL)  // 64
#define LOG2E 1.44269504088896340736f

typedef float f32x4 __attribute__((ext_vector_type(4)));
// Guide-verified fragment type for mfma_f32_16x16x32_bf16 on gfx950:
// 8 bf16 carried as 8 shorts (4 VGPRs).
typedef short bf16x8 __attribute__((ext_vector_type(8)));

// round-to-nearest-even f32 -> bf16 (as ushort bits)
__device__ __forceinline__ unsigned short f2bf(float x) {
  unsigned u = __float_as_uint(x);
  u = u + 0x7fffu + ((u >> 16) & 1u);
  return (unsigned short)(u >> 16);
}
__device__ __forceinline__ float bf2f(unsigned short h) {
  return __uint_as_float(((unsigned)h) << 16);
}

// ---------------- K0: At/Wbct prep + W1/W2 hi-lo bf16 fragment packing ------
// Fragment layout (consistent K-enumeration for A and B operands of
// mfma_f32_16x16x32_bf16): element j of lane l covers k = s*32 + 8*(l>>4)+j,
// 16-dim = lane&15. Works for ANY internal HW k-map since A and B share it.
__global__ __launch_bounds__(256) void k0_prep(const float* __restrict__ A,
                                               const float* __restrict__ WB,
                                               const float* __restrict__ WC,
                                               const float* __restrict__ W1,
                                               const float* __restrict__ W2,
                                               float* __restrict__ At,
                                               float* __restrict__ Wbct,
                                               unsigned short* __restrict__ W1fh,
                                               unsigned short* __restrict__ W1fl,
                                               unsigned short* __restrict__ W2fh,
                                               unsigned short* __restrict__ W2fl) {
  int i = blockIdx.x * 256 + threadIdx.x;  // 86016 total
  if (i < 4096) {
    int d = i >> 4, n = i & 15;
    At[n * D + d] = A[i] * LOG2E;
  } else if (i < 12288) {
    int j = i - 4096;  // 8192
    int d = j >> 5, c = j & 31;
    Wbct[j] = (c < 16) ? WB[c * D + d] : WC[(c - 16) * D + d];
  } else if (i < 77824) {
    // W1 frags: e = ((s*16 + t)*64 + l)*8 + j ; 65536 elems
    int e = i - 12288;
    int j = e & 7, l = (e >> 3) & 63, tt = (e >> 9) & 15, s = e >> 13;
    int k = s * 32 + ((l >> 4) << 3) + j;
    int n = tt * 16 + (l & 15);
    float x = W1[k * 256 + n];
    unsigned short h = f2bf(x);
    W1fh[e] = h;
    W1fl[e] = f2bf(x - bf2f(h));
  } else {
    // W2 frags: e = ((s*2 + t)*64 + l)*8 + j ; 8192 elems
    int e = i - 77824;
    int j = e & 7, l = (e >> 3) & 63, tt = (e >> 9) & 1, s = e >> 10;
    int k = s * 32 + ((l >> 4) << 3) + j;
    int n = tt * 16 + (l & 15);
    float x = W2[k * 32 + n];
    unsigned short h = f2bf(x);
    W2fh[e] = h;
    W2fl[e] = f2bf(x - bf2f(h));
  }
}

// ---------------- K1a: front end + LOCAL CHUNK SCAN fused (unchanged) ------
__global__ __launch_bounds__(256) void k1a_front_scan(
    const float* __restrict__ y, const float* __restrict__ Win,
    const float* __restrict__ bin_, const float* __restrict__ ng,
    const float* __restrict__ nb, const float* __restrict__ Wbct,
    const float* __restrict__ qd, const float* __restrict__ pd,
    const float* __restrict__ At,
    float* __restrict__ hn, float* __restrict__ delta,
    float* __restrict__ Bm, float* __restrict__ Cm,
    float* __restrict__ muv, float* __restrict__ irsv,
    float* __restrict__ EX, float* __restrict__ T) {
  __shared__ float sy[32][32];
  __shared__ float sh[32][260];   // hn tile, pitch 260
  __shared__ float sB[32][NX];
  __shared__ float sdelta[32];
  int t = threadIdx.x;
  int tok0 = blockIdx.x * 32;     // blockIdx.x == global chunk index b*NCH+ch
  {
    const float4* src = (const float4*)(y + (size_t)tok0 * 32);
    ((float4*)sy)[t] = src[t];
  }
  __syncthreads();
  int dcol = t & 63;
  int jrow = t >> 6;
  int d4 = dcol * 4;
  float4 bv = ((const float4*)bin_)[dcol];
  float4 acc[8];
  #pragma unroll
  for (int jj = 0; jj < 8; ++jj) acc[jj] = bv;
  const float4* Win4 = (const float4*)Win;
  #pragma unroll
  for (int k = 0; k < 32; ++k) {
    float4 wv = Win4[k * 64 + dcol];
    #pragma unroll
    for (int jj = 0; jj < 8; ++jj) {
      float av = sy[jrow * 8 + jj][k];
      acc[jj].x = fmaf(av, wv.x, acc[jj].x);
      acc[jj].y = fmaf(av, wv.y, acc[jj].y);
      acc[jj].z = fmaf(av, wv.z, acc[jj].z);
      acc[jj].w = fmaf(av, wv.w, acc[jj].w);
    }
  }
  float4 g4 = ((const float4*)ng)[dcol];
  float4 nb4 = ((const float4*)nb)[dcol];
  float4 q4 = ((const float4*)qd)[dcol];
  float pd0 = pd[0];
  #pragma unroll
  for (int jj = 0; jj < 8; ++jj) {
    int j = jrow * 8 + jj;
    int tok = tok0 + j;
    float4 a = acc[jj];
    float s1 = a.x + a.y + a.z + a.w;
    float s2 = a.x * a.x + a.y * a.y + a.z * a.z + a.w * a.w;
    #pragma unroll
    for (int off = 1; off < 64; off <<= 1) {
      s1 += __shfl_xor(s1, off);
      s2 += __shfl_xor(s2, off);
    }
    float mu = s1 * (1.f / D);
    float var = s2 * (1.f / D) - mu * mu;
    float rstd = rsqrtf(var + 1e-5f);
    if (dcol == 0) { muv[tok] = mu; irsv[tok] = sqrtf(var + 1e-5f); }
    float4 v4;
    v4.x = (a.x - mu) * rstd * g4.x + nb4.x;
    v4.y = (a.y - mu) * rstd * g4.y + nb4.y;
    v4.z = (a.z - mu) * rstd * g4.z + nb4.z;
    v4.w = (a.w - mu) * rstd * g4.w + nb4.w;
    ((float4*)(hn + (size_t)tok * D))[dcol] = v4;
    *(float4*)&sh[j][d4] = v4;
    float dd = v4.x * q4.x + v4.y * q4.y + v4.z * q4.z + v4.w * q4.w;
    #pragma unroll
    for (int off = 1; off < 64; off <<= 1) dd += __shfl_xor(dd, off);
    if (dcol == 0) {
      float xx = pd0 + dd;
      float dv = (xx > 20.f) ? xx : log1pf(expf(xx));
      delta[tok] = dv;
      sdelta[j] = dv;
    }
  }
  __syncthreads();
  // chunk delta total (wave 0, lanes 0..31)
  if (t < 32) {
    float v = sdelta[t];
    #pragma unroll
    for (int off = 1; off < 32; off <<= 1) v += __shfl_xor(v, off);
    if (t == 0) T[blockIdx.x] = v;
  }
  // Phase C: [Bm|Cm] = sh @ Wbct; keep B columns in sB for the scan
  int col4 = t & 7;
  int j = t >> 3;
  const float4* W4 = (const float4*)Wbct;
  float4 o = make_float4(0.f, 0.f, 0.f, 0.f);
  #pragma unroll 8
  for (int d = 0; d < 256; ++d) {
    float av = sh[j][d];
    float4 w = W4[d * 8 + col4];
    o.x = fmaf(av, w.x, o.x);
    o.y = fmaf(av, w.y, o.y);
    o.z = fmaf(av, w.z, o.z);
    o.w = fmaf(av, w.w, o.w);
  }
  int tokj = tok0 + j;
  if (col4 < 4) {
    ((float4*)(Bm + (size_t)tokj * NX))[col4] = o;
    *(float4*)&sB[j][col4 * 4] = o;
  } else {
    ((float4*)(Cm + (size_t)tokj * NX))[col4 - 4] = o;
  }
  __syncthreads();
  // Scan phase: thread = d, state x[16] in regs, zero init
  float a16[16];
  #pragma unroll
  for (int n = 0; n < 16; ++n) a16[n] = At[n * D + t];
  float x16[16];
  #pragma unroll
  for (int n = 0; n < 16; ++n) x16[n] = 0.f;
  for (int lo = 0; lo < CL; ++lo) {
    float dlt = sdelta[lo];
    float du = dlt * sh[lo][t];
    #pragma unroll
    for (int n = 0; n < 16; ++n)
      x16[n] = fmaf(exp2f(dlt * a16[n]), x16[n], du * sB[lo][n]);
  }
  size_t exbase = (size_t)blockIdx.x * (NX * D) + t;
  #pragma unroll
  for (int n = 0; n < 16; ++n) EX[exbase + n * D] = x16[n];
}

// ---------------- K2b: chunk-level scan, in-place E -> X (unchanged) -------
__global__ __launch_bounds__(256) void k2b_chunkscan(
    const float* __restrict__ At, const float* __restrict__ T,
    float* __restrict__ EX) {
  __shared__ float sT[NCH];
  int b = blockIdx.x >> 4;
  int rem = ((blockIdx.x & 15) << 8) | threadIdx.x;  // n*D + d
  if (threadIdx.x < NCH) sT[threadIdx.x] = T[b * NCH + threadIdx.x];
  __syncthreads();
  float A2 = At[rem];  // already *LOG2E
  size_t base = ((size_t)b << 18) + rem;
  float eq[4];
  #pragma unroll
  for (int j = 0; j < 4; ++j) eq[j] = EX[base + ((size_t)j << 12)];
  float x = 0.f;
  #pragma unroll 4
  for (int c = 0; c < NCH; ++c) {
    float e = eq[c & 3];
    if (c + 4 < NCH) eq[c & 3] = EX[base + ((size_t)(c + 4) << 12)];
    EX[base + ((size_t)c << 12)] = x;
    x = fmaf(exp2f(sT[c] * A2), x, e);
  }
}

__device__ __forceinline__ float gelu_exact(float x) {
  return 0.5f * x * (1.f + erff(x * 0.70710678118654752440f));
}

// ---------------- K2cd: fixup scan + h recon + LN2 + MFMA MLP ---------------
// Scan/LN2 as before; MLP with bf16 hi/lo split MFMA (3 passes:
// Ah*Bh + Al*Bh + Ah*Bl, dropped Al*Bl ~2^-18 rel). A-tiles in LDS as bf16
// row-major [32][256] with XOR swizzle byte^=((row&7)<<4); W1/W2 fragments
// pre-packed in workspace (k0) with the SAME K-enumeration as the A-frag
// reads -> correct for any internal HW k-map.
__global__ __launch_bounds__(256) void k2cd_scan_mlp(
    const float* __restrict__ hn, const float* __restrict__ delta,
    const float* __restrict__ Bm, const float* __restrict__ Cm,
    const float* __restrict__ At, const float* __restrict__ EX,
    const float* __restrict__ muv, const float* __restrict__ irsv,
    const float* __restrict__ ng, const float* __restrict__ nb,
    const float* __restrict__ nfg, const float* __restrict__ nfb,
    const unsigned short* __restrict__ W1fh, const unsigned short* __restrict__ W1fl,
    const unsigned short* __restrict__ W2fh, const unsigned short* __restrict__ W2fl,
    const float* __restrict__ b1, const float* __restrict__ b2,
    float* __restrict__ out) {
  __shared__ float s_az[32 * 260];                       // scan output (pre-LN2)
  __shared__ __align__(16) unsigned short sAh[32 * 256]; // bf16 hi (a-tile, then z)
  __shared__ __align__(16) unsigned short sAl[32 * 256]; // bf16 lo
  __shared__ float sB[32][NX];
  __shared__ float sC[32][NX];
  __shared__ float sdelta[32];
  __shared__ float smu[32];
  __shared__ float sirs[32];
  int t = threadIdx.x;
  int tok0 = blockIdx.x * 32;  // blockIdx.x == global chunk index
  size_t tokbase = (size_t)tok0;
  if (t < 32) {
    sdelta[t] = delta[tokbase + t];
    smu[t] = muv[tokbase + t];
    sirs[t] = irsv[tokbase + t];
  }
  for (int i = t; i < 32 * NX; i += 256) {
    ((float*)sB)[i] = Bm[tokbase * NX + i];
    ((float*)sC)[i] = Cm[tokbase * NX + i];
  }
  float a16[16], x16[16];
  size_t exbase = (size_t)blockIdx.x * (NX * D) + t;
  #pragma unroll
  for (int n = 0; n < 16; ++n) {
    a16[n] = At[n * D + t];
    x16[n] = EX[exbase + n * D];
  }
  float nb_d = nb[t];
  float invg = 1.0f / ng[t];
  __syncthreads();
  // scan with true entering state; hn read straight from global (used once)
  for (int lo = 0; lo < CL; ++lo) {
    float hv = hn[(tokbase + lo) * D + t];  // coalesced 1 KB/wave
    float dlt = sdelta[lo];
    float du = dlt * hv;
    float p = 0.f;
    #pragma unroll
    for (int n = 0; n < 16; ++n) {
      x16[n] = fmaf(exp2f(dlt * a16[n]), x16[n], du * sB[lo][n]);
      p = fmaf(x16[n], sC[lo][n], p);
    }
    float h = fmaf((hv - nb_d) * invg, sirs[lo], smu[lo]);
    s_az[lo * 260 + t] = h + p;  // final pre-LN2 value
  }
  __syncthreads();
  // LN2 (wave w owns tokens w*8..+7) -> bf16 hi/lo A-tile, XOR-swizzled
  int dcol = t & 63, jrow = t >> 6;
  int d4 = dcol * 4, j8 = jrow * 8;
  {
    float4 g4 = ((const float4*)nfg)[dcol];
    float4 b4 = ((const float4*)nfb)[dcol];
    for (int jj = 0; jj < 8; ++jj) {
      int lo = j8 + jj;
      float4 v = *(float4*)&s_az[lo * 260 + d4];
      float s1 = v.x + v.y + v.z + v.w;
      float s2 = v.x * v.x + v.y * v.y + v.z * v.z + v.w * v.w;
      #pragma unroll
      for (int off = 1; off < 64; off <<= 1) {
        s1 += __shfl_xor(s1, off);
        s2 += __shfl_xor(s2, off);
      }
      float mu2 = s1 * (1.f / D);
      float var2 = s2 * (1.f / D) - mu2 * mu2;
      float rstd2 = rsqrtf(var2 + 1e-5f);
      float4 o;
      o.x = (v.x - mu2) * rstd2 * g4.x + b4.x;
      o.y = (v.y - mu2) * rstd2 * g4.y + b4.y;
      o.z = (v.z - mu2) * rstd2 * g4.z + b4.z;
      o.w = (v.w - mu2) * rstd2 * g4.w + b4.w;
      unsigned short h0 = f2bf(o.x), h1 = f2bf(o.y), h2 = f2bf(o.z), h3 = f2bf(o.w);
      unsigned short q0 = f2bf(o.x - bf2f(h0));
      unsigned short q1 = f2bf(o.y - bf2f(h1));
      unsigned short q2 = f2bf(o.z - bf2f(h2));
      unsigned short q3 = f2bf(o.w - bf2f(h3));
      unsigned off16 = ((unsigned)(d4 * 2)) ^ ((unsigned)(lo & 7) << 4);
      uint2 hv2, lv2;
      hv2.x = (unsigned)h0 | ((unsigned)h1 << 16);
      hv2.y = (unsigned)h2 | ((unsigned)h3 << 16);
      lv2.x = (unsigned)q0 | ((unsigned)q1 << 16);
      lv2.y = (unsigned)q2 | ((unsigned)q3 << 16);
      *(uint2*)((char*)sAh + lo * 512 + off16) = hv2;
      *(uint2*)((char*)sAl + lo * 512 + off16) = lv2;
    }
  }
  __syncthreads();
  // ---- GEMM1: (32x256) @ W1 (256x256), wave w owns cols [w*64, w*64+64) ----
  int l = t & 63, w = t >> 6;
  const bf16x8* B1h = (const bf16x8*)W1fh;
  const bf16x8* B1l = (const bf16x8*)W1fl;
  f32x4 acc[2][4];
  #pragma unroll
  for (int m = 0; m < 2; ++m)
    #pragma unroll
    for (int n = 0; n < 4; ++n) {
      f32x4 z4 = {0.f, 0.f, 0.f, 0.f};
      acc[m][n] = z4;
    }
  #pragma unroll 2
  for (int s = 0; s < 8; ++s) {
    bf16x8 ah[2], al[2];
    #pragma unroll
    for (int m = 0; m < 2; ++m) {
      int row = m * 16 + (l & 15);
      unsigned off16 = ((unsigned)(s * 64 + ((l >> 4) << 4))) ^ ((unsigned)(row & 7) << 4);
      ah[m] = *(const bf16x8*)((const char*)sAh + row * 512 + off16);
      al[m] = *(const bf16x8*)((const char*)sAl + row * 512 + off16);
    }
    #pragma unroll
    for (int n = 0; n < 4; ++n) {
      int bi = (s * 16 + w * 4 + n) * 64 + l;
      bf16x8 bh = B1h[bi];
      bf16x8 bl = B1l[bi];
      #pragma unroll
      for (int m = 0; m < 2; ++m) {
        acc[m][n] = __builtin_amdgcn_mfma_f32_16x16x32_bf16(ah[m], bh, acc[m][n], 0, 0, 0);
        acc[m][n] = __builtin_amdgcn_mfma_f32_16x16x32_bf16(al[m], bh, acc[m][n], 0, 0, 0);
        acc[m][n] = __builtin_amdgcn_mfma_f32_16x16x32_bf16(ah[m], bl, acc[m][n], 0, 0, 0);
      }
    }
  }
  __syncthreads();  // all A-tile reads done; sAh/sAl now reused for z
  // ---- b1 + gelu + convert -> z (bf16 hi/lo) back into sAh/sAl ----
  #pragma unroll
  for (int n = 0; n < 4; ++n) {
    int colz = w * 64 + n * 16 + (l & 15);
    float b1v = b1[colz];
    #pragma unroll
    for (int m = 0; m < 2; ++m) {
      #pragma unroll
      for (int r = 0; r < 4; ++r) {
        int row = m * 16 + ((l >> 4) << 2) + r;  // C/D: row=(lane>>4)*4+reg
        float zv = gelu_exact(acc[m][n][r] + b1v);
        unsigned short zh = f2bf(zv);
        unsigned short zl = f2bf(zv - bf2f(zh));
        unsigned off16 = ((unsigned)(colz * 2)) ^ ((unsigned)(row & 7) << 4);
        *(unsigned short*)((char*)sAh + row * 512 + off16) = zh;
        *(unsigned short*)((char*)sAl + row * 512 + off16) = zl;
      }
    }
  }
  __syncthreads();
  // ---- GEMM2: z (32x256) @ W2 (256x32); wave w -> (mw=w>>1, nw=w&1) ----
  int mw = w >> 1, nw = w & 1;
  const bf16x8* B2h = (const bf16x8*)W2fh;
  const bf16x8* B2l = (const bf16x8*)W2fl;
  f32x4 acc2 = {0.f, 0.f, 0.f, 0.f};
  #pragma unroll 2
  for (int s = 0; s < 8; ++s) {
    int row = mw * 16 + (l & 15);
    unsigned off16 = ((unsigned)(s * 64 + ((l >> 4) << 4))) ^ ((unsigned)(row & 7) << 4);
    bf16x8 zh8 = *(const bf16x8*)((const char*)sAh + row * 512 + off16);
    bf16x8 zl8 = *(const bf16x8*)((const char*)sAl + row * 512 + off16);
    int bi = (s * 2 + nw) * 64 + l;
    bf16x8 bh = B2h[bi];
    bf16x8 bl = B2l[bi];
    acc2 = __builtin_amdgcn_mfma_f32_16x16x32_bf16(zh8, bh, acc2, 0, 0, 0);
    acc2 = __builtin_amdgcn_mfma_f32_16x16x32_bf16(zl8, bh, acc2, 0, 0, 0);
    acc2 = __builtin_amdgcn_mfma_f32_16x16x32_bf16(zh8, bl, acc2, 0, 0, 0);
  }
  int colo = nw * 16 + (l & 15);
  float b2v = b2[colo];
  #pragma unroll
  for (int r = 0; r < 4; ++r) {
    int row = mw * 16 + ((l >> 4) << 2) + r;
    out[(size_t)(tok0 + row) * 32 + colo] = acc2[r] + b2v;
  }
}

extern "C" void kernel_launch(void* const* d_in, const int* in_sizes, int n_in,
                              void* d_out, int out_size, void* d_ws, size_t ws_size,
                              hipStream_t stream) {
  const float* y    = (const float*)d_in[0];
  const float* Win  = (const float*)d_in[1];
  const float* bin_ = (const float*)d_in[2];
  const float* ng   = (const float*)d_in[3];
  const float* nb   = (const float*)d_in[4];
  const float* A    = (const float*)d_in[5];
  const float* WB   = (const float*)d_in[6];
  const float* WC   = (const float*)d_in[7];
  const float* qd   = (const float*)d_in[8];
  const float* pd   = (const float*)d_in[9];
  const float* nfg  = (const float*)d_in[10];
  const float* nfb  = (const float*)d_in[11];
  const float* W1   = (const float*)d_in[12];
  const float* b1   = (const float*)d_in[13];
  const float* W2   = (const float*)d_in[14];
  const float* b2   = (const float*)d_in[15];

  float* ws = (float*)d_ws;
  float* hnbuf = ws;                          // NTOK*D
  float* delta = ws + 4194304;                // NTOK
  float* Bm    = delta + NTOK;                // NTOK*NX
  float* Cm    = Bm + NTOK * NX;              // NTOK*NX
  float* muv   = Cm + NTOK * NX;              // NTOK
  float* irsv  = muv + NTOK;                  // NTOK
  float* Tbuf  = irsv + NTOK;                 // 512
  float* At    = Tbuf + NBATCH * NCH;         // 4096
  float* Wbct  = At + D * NX;                 // 8192
  float* EX    = Wbct + D * 32;               // 512*4096 = 2M floats
  // bf16 fragment-packed MLP weights (hi/lo): 147456 ushorts = 288 KB
  unsigned short* W1fh = (unsigned short*)(EX + 2097152);  // 65536
  unsigned short* W1fl = W1fh + 65536;                     // 65536
  unsigned short* W2fh = W1fl + 65536;                     // 8192
  unsigned short* W2fl = W2fh + 8192;                      // 8192

  k0_prep<<<336, 256, 0, stream>>>(A, WB, WC, W1, W2, At, Wbct,
                                   W1fh, W1fl, W2fh, W2fl);
  k1a_front_scan<<<NTOK / 32, 256, 0, stream>>>(y, Win, bin_, ng, nb, Wbct,
                                                qd, pd, At, hnbuf, delta, Bm,
                                                Cm, muv, irsv, EX, Tbuf);
  k2b_chunkscan<<<NBATCH * 16, 256, 0, stream>>>(At, Tbuf, EX);
  k2cd_scan_mlp<<<NTOK / 32, 256, 0, stream>>>(hnbuf, delta, Bm, Cm, At, EX,
                                               muv, irsv, ng, nb, nfg, nfb,
                                               W1fh, W1fl, W2fh, W2fl,
                                               b1, b2, (float*)d_out);
}